// Round 8
// baseline (56.876 us; speedup 1.0000x reference)
//
#include <hip/hip_runtime.h>
#include <hip/hip_fp16.h>

#define D      128
#define NROWS  100000
#define RB     64                       // rows per E-block (32 KB LDS)
#define NE     ((NROWS + RB - 1) / RB)  // 1563

typedef __attribute__((ext_vector_type(8))) _Float16 f16x8;
typedef __attribute__((ext_vector_type(2))) _Float16 f16x2;
typedef __attribute__((ext_vector_type(4))) float    f32x4;

union F16x8U { _Float16 h[8]; f16x8 v; };
union F32x4U { float f[4]; f32x4 v; };

typedef __attribute__((address_space(1))) const void gvoid;
typedef __attribute__((address_space(3))) void       lvoid;

// ---------------------------------------------------------------------------
// Kernel 0: metric -> fragment-ordered fp16 hi/lo B-fragments.
// Chunk q = (kk*8+cf)*64+lane holds B[k0+j][col], col=cf*16+(lane&15),
// k0=kk*32+(lane>>4)*8  == the 16x16x32 MFMA B-operand layout.
// fp16 two-term split: M = Mh + Ml, |residual| ~ 2^-22 |M|.
// ---------------------------------------------------------------------------
__global__ __launch_bounds__(256) void convert_M16(
    const float* __restrict__ M,
    _Float16* __restrict__ mh, _Float16* __restrict__ ml)
{
    const int q    = blockIdx.x * 256 + threadIdx.x;  // [0, 2048)
    const int kk   = q >> 9;
    const int cf   = (q >> 6) & 7;
    const int lane = q & 63;
    const int col  = cf * 16 + (lane & 15);
    const int k0   = kk * 32 + (lane >> 4) * 8;

    F16x8U h, l;
    #pragma unroll
    for (int j = 0; j < 8; ++j) {
        float f = M[(k0 + j) * D + col];
        _Float16 hh = (_Float16)f;
        h.h[j] = hh;
        l.h[j] = (_Float16)(f - (float)hh);
    }
    *(f16x8*)(mh + q * 8) = h.v;
    *(f16x8*)(ml + q * 8) = l.v;
}

// ---------------------------------------------------------------------------
// Kernel 1: E' = E @ M (two-term fp16 MFMA), output fp16 in pi order,
// pi(c) = (c&15)*8 + (c>>4). Pure E grid (N-convert eliminated this round).
// 64 rows x 128 cols per block, 4 waves; wave w owns 32 COLS (all 64 rows):
// its 16 B-frags (64 VGPR) load once -- issued FIRST so their latency hides
// under the stage issue, anchored after the drain with an asm "+v" pin so
// they cannot be re-sunk into the MFMA loop. A staged via global_load_lds
// (async, XOR-swizzled via pre-swizzled GLOBAL source, m173); proven drain
// = vmcnt(0) + __syncthreads (R5's barrier-less variant raced).
// ---------------------------------------------------------------------------
__global__ __launch_bounds__(256, 3) void gemm_E(
    const float* __restrict__ E,
    const _Float16* __restrict__ mh, const _Float16* __restrict__ ml,
    _Float16* __restrict__ Ep)
{
    __shared__ float lds[RB * D];   // 32 KB

    const int tid  = threadIdx.x;
    const int lane = tid & 63;
    const int w    = tid >> 6;
    const int rb   = (int)blockIdx.x * RB;
    const int lrow = lane & 15;
    const int lk   = lane >> 4;

    // Wave w's 16 B-fragments (cols w*32..+31) -- issue before the stage.
    f16x8 bh[4][2], bl[4][2];
    #pragma unroll
    for (int kk = 0; kk < 4; ++kk)
        #pragma unroll
        for (int cfl = 0; cfl < 2; ++cfl) {
            const int off = ((kk * 8 + w * 2 + cfl) * 64 + lane) * 8;
            bh[kk][cfl] = *(const f16x8*)(mh + off);
            bl[kk][cfl] = *(const f16x8*)(ml + off);
        }

    // Stage A: 16B-slot S = w*512 + i*64 + lane; r = S>>5 (row), t = S&31;
    // global slot u = t ^ (r&15); LDS dest linear (wave-uniform base + lane*16).
    #pragma unroll
    for (int i = 0; i < 8; ++i) {
        const int S  = w * 512 + i * 64 + lane;
        const int r  = S >> 5;
        const int u  = (S & 31) ^ (r & 15);
        const int gr = min(rb + r, NROWS - 1);          // tail clamp
        const float* src = E + (size_t)gr * D + u * 4;
        __builtin_amdgcn_global_load_lds(
            (gvoid*)src, (lvoid*)&lds[(w * 512 + i * 64) * 4], 16, 0, 0);
    }

    f32x4 acc[4][2];
    #pragma unroll
    for (int rf = 0; rf < 4; ++rf)
        #pragma unroll
        for (int cfl = 0; cfl < 2; ++cfl)
            acc[rf][cfl] = (f32x4){0.f, 0.f, 0.f, 0.f};

    // Proven drain: full waitcnt + block barrier.
    asm volatile("s_waitcnt vmcnt(0)" ::: "memory");
    __syncthreads();
    __builtin_amdgcn_sched_barrier(0);

    // Anchor B-fragments here: creates a def/use point after the drain so
    // the loads stay hoisted and the values stay in registers for the loop.
    #pragma unroll
    for (int kk = 0; kk < 4; ++kk)
        #pragma unroll
        for (int cfl = 0; cfl < 2; ++cfl)
            asm volatile("" : "+v"(bh[kk][cfl]), "+v"(bl[kk][cfl]));

    #pragma unroll
    for (int kk = 0; kk < 4; ++kk) {
        // A fragments: row r = rf*16 + lrow, 16B slot t = (kk*8+lk*2) ^ (r&15).
        F16x8U a16[4];
        #pragma unroll
        for (int rf = 0; rf < 4; ++rf) {
            const int r  = rf * 16 + lrow;
            const int t0 = kk * 8 + lk * 2;
            F32x4U x, y;
            x.v = *(const f32x4*)&lds[(r * 32 + ((t0    ) ^ (r & 15))) * 4];
            y.v = *(const f32x4*)&lds[(r * 32 + ((t0 + 1) ^ (r & 15))) * 4];
            #pragma unroll
            for (int j = 0; j < 4; ++j) {
                a16[rf].h[j]     = (_Float16)x.f[j];
                a16[rf].h[j + 4] = (_Float16)y.f[j];
            }
        }

        #pragma unroll
        for (int rf = 0; rf < 4; ++rf)
            #pragma unroll
            for (int cfl = 0; cfl < 2; ++cfl) {
                acc[rf][cfl] = __builtin_amdgcn_mfma_f32_16x16x32_f16(
                    a16[rf].v, bh[kk][cfl], acc[rf][cfl], 0, 0, 0);
                acc[rf][cfl] = __builtin_amdgcn_mfma_f32_16x16x32_f16(
                    a16[rf].v, bl[kk][cfl], acc[rf][cfl], 0, 0, 0);
            }
    }

    // Epilogue: C/D layout col=lane&15, row=(lane>>4)*4+i (m89-verified).
    // Global col c = w*32 + cfl*16 + lrow; pi(c) = lrow*8 + w*2 + cfl ->
    // the 2 cfl values are adjacent: one f16x2 (4B) store per (rf,i).
    #pragma unroll
    for (int rf = 0; rf < 4; ++rf)
        #pragma unroll
        for (int i = 0; i < 4; ++i) {
            const int row = rb + rf * 16 + lk * 4 + i;
            if (row < NROWS) {
                f16x2 o;
                o[0] = (_Float16)acc[rf][0][i];
                o[1] = (_Float16)acc[rf][1][i];
                *(f16x2*)(Ep + (size_t)row * D + lrow * 8 + w * 2) = o;
            }
        }
}

// ---------------------------------------------------------------------------
// Kernel 2: out[b] = sigmoid(2 * dot(Ep16[xs[b]], N[ys[b]]) - 1).
// Ep is fp16 in pi order: lane l's f16x8 slot j holds col c = l + 16j, which
// pairs with N[y][l + 16j] (fp32, exact). The N reads coalesce into 64B
// segments per 16-lane group. 2 outputs per lane-group, fp32 accumulate.
// ---------------------------------------------------------------------------
__global__ __launch_bounds__(256) void gather_dotN(
    const int* __restrict__ xs, const int* __restrict__ ys,
    const _Float16* __restrict__ Ep, const float* __restrict__ N,
    float* __restrict__ out)
{
    const int tid = threadIdx.x;
    const int o0  = blockIdx.x * 32 + (tid >> 4) * 2;
    const int l   = tid & 15;

    const int x0 = xs[o0], x1 = xs[o0 + 1];
    const int y0 = ys[o0], y1 = ys[o0 + 1];

    const f16x8 a0 = *(const f16x8*)(Ep + (size_t)x0 * D + l * 8);
    const f16x8 a1 = *(const f16x8*)(Ep + (size_t)x1 * D + l * 8);
    const float* n0 = N + (size_t)y0 * D + l;
    const float* n1 = N + (size_t)y1 * D + l;

    float r0 = 0.f, r1 = 0.f;
    #pragma unroll
    for (int j = 0; j < 8; ++j) {
        r0 += (float)a0[j] * n0[16 * j];
        r1 += (float)a1[j] * n1[16 * j];
    }

    r0 += __shfl_xor(r0, 1); r1 += __shfl_xor(r1, 1);
    r0 += __shfl_xor(r0, 2); r1 += __shfl_xor(r1, 2);
    r0 += __shfl_xor(r0, 4); r1 += __shfl_xor(r1, 4);
    r0 += __shfl_xor(r0, 8); r1 += __shfl_xor(r1, 8);

    if (l == 0) {
        float2 v;
        v.x = 1.0f / (1.0f + __expf(1.0f - 2.0f * r0));
        v.y = 1.0f / (1.0f + __expf(1.0f - 2.0f * r1));
        *(float2*)(out + o0) = v;
    }
}

extern "C" void kernel_launch(void* const* d_in, const int* in_sizes, int n_in,
                              void* d_out, int out_size, void* d_ws, size_t ws_size,
                              hipStream_t stream) {
    const int*   xs     = (const int*)d_in[0];
    const int*   ys     = (const int*)d_in[1];
    const float* metric = (const float*)d_in[2];
    const float* EMBEDM = (const float*)d_in[3];
    const float* NEGEM  = (const float*)d_in[4];
    float*       out    = (float*)d_out;

    const int B = in_sizes[0];  // 262144

    // d_ws layout: Ep16 25.6MB @0, M-frag fp16 hi/lo @64MB.
    char* ws = (char*)d_ws;
    _Float16* Ep = (_Float16*)ws;
    _Float16* mh = (_Float16*)(ws + (64u << 20));
    _Float16* ml = (_Float16*)(ws + (64u << 20) + (64u << 10));

    convert_M16<<<8, 256, 0, stream>>>(metric, mh, ml);

    gemm_E<<<NE, 256, 0, stream>>>(EMBEDM, mh, ml, Ep);

    gather_dotN<<<B / 32, 256, 0, stream>>>(xs, ys, Ep, NEGEM, out);
}

// Round 9
// 56.480 us; speedup vs baseline: 1.0070x; 1.0070x over previous
//
#include <hip/hip_runtime.h>
#include <hip/hip_fp16.h>

#define D      128
#define NROWS  100000
#define RB     64                         // rows per tile (32 KB LDS per buffer)
#define NTILES ((NROWS + RB - 1) / RB)    // 1563
#define GRID_E 512                        // 2 blocks/CU exactly; ~3 tiles/block

typedef __attribute__((ext_vector_type(8))) _Float16 f16x8;
typedef __attribute__((ext_vector_type(2))) _Float16 f16x2;
typedef __attribute__((ext_vector_type(4))) float    f32x4;

union F16x8U { _Float16 h[8]; f16x8 v; };
union F32x4U { float f[4]; f32x4 v; };

typedef __attribute__((address_space(1))) const void gvoid;
typedef __attribute__((address_space(3))) void       lvoid;

// ---------------------------------------------------------------------------
// Kernel 0: metric -> fragment-ordered fp16 hi/lo B-fragments.
// Chunk q = (kk*8+cf)*64+lane holds B[k0+j][col], col=cf*16+(lane&15),
// k0=kk*32+(lane>>4)*8  == the 16x16x32 MFMA B-operand layout.
// fp16 two-term split: M = Mh + Ml, |residual| ~ 2^-22 |M|.
// ---------------------------------------------------------------------------
__global__ __launch_bounds__(256) void convert_M16(
    const float* __restrict__ M,
    _Float16* __restrict__ mh, _Float16* __restrict__ ml)
{
    const int q    = blockIdx.x * 256 + threadIdx.x;  // [0, 2048)
    const int kk   = q >> 9;
    const int cf   = (q >> 6) & 7;
    const int lane = q & 63;
    const int col  = cf * 16 + (lane & 15);
    const int k0   = kk * 32 + (lane >> 4) * 8;

    F16x8U h, l;
    #pragma unroll
    for (int j = 0; j < 8; ++j) {
        float f = M[(k0 + j) * D + col];
        _Float16 hh = (_Float16)f;
        h.h[j] = hh;
        l.h[j] = (_Float16)(f - (float)hh);
    }
    *(f16x8*)(mh + q * 8) = h.v;
    *(f16x8*)(ml + q * 8) = l.v;
}

// ---------------------------------------------------------------------------
// Stage one 64x128 fp32 tile into LDS via global_load_lds.
// 16B-slot S = w*512 + i*64 + lane; r = S>>5 (tile row), t = S&31;
// global 16B-col u = t ^ (r&15) (m173 source-side XOR swizzle; LDS dest
// linear: wave-uniform base, HW adds lane*16).
// ---------------------------------------------------------------------------
__device__ __forceinline__ void stage_tile(
    const float* __restrict__ E, float* Lbase, int rb, int w, int lane)
{
    #pragma unroll
    for (int i = 0; i < 8; ++i) {
        const int S  = w * 512 + i * 64 + lane;
        const int r  = S >> 5;
        const int u  = (S & 31) ^ (r & 15);
        const int gr = min(rb + r, NROWS - 1);          // tail clamp
        const float* src = E + (size_t)gr * D + u * 4;
        __builtin_amdgcn_global_load_lds(
            (gvoid*)src, (lvoid*)(Lbase + (w * 512 + i * 64) * 4), 16, 0, 0);
    }
}

// ---------------------------------------------------------------------------
// Kernel 1: E' = E @ M (two-term fp16 MFMA), fp16 output in pi order,
// pi(c) = (c&15)*8 + (c>>4).
// T3 "minimum 2-phase" pipeline: persistent blocks, double-buffered LDS.
// Per tile: STAGE(next) -> COMPUTE(cur) -> vmcnt(0)+__syncthreads (drain
// finds next-tile loads already complete; proven-safe barrier structure)
// -> STORE(cur, overlaps next compute window). B-fragments load once/block.
// Wave w owns 32 cols x all 64 rows; 16 B-frags in 64 VGPR, acc[4][2].
// ---------------------------------------------------------------------------
__global__ __launch_bounds__(256, 2) void gemm_E(
    const float* __restrict__ E,
    const _Float16* __restrict__ mh, const _Float16* __restrict__ ml,
    _Float16* __restrict__ Ep)
{
    __shared__ float lds[2][RB * D];   // 2 x 32 KB

    const int tid  = threadIdx.x;
    const int lane = tid & 63;
    const int w    = tid >> 6;
    const int lrow = lane & 15;
    const int lk   = lane >> 4;

    // Wave w's 16 B-fragments (cols w*32..+31), loaded ONCE per block.
    f16x8 bh[4][2], bl[4][2];
    #pragma unroll
    for (int kk = 0; kk < 4; ++kk)
        #pragma unroll
        for (int cfl = 0; cfl < 2; ++cfl) {
            const int off = ((kk * 8 + w * 2 + cfl) * 64 + lane) * 8;
            bh[kk][cfl] = *(const f16x8*)(mh + off);
            bl[kk][cfl] = *(const f16x8*)(ml + off);
        }

    // Prologue: stage first tile into buffer 0, full drain + barrier.
    const int t0 = (int)blockIdx.x;
    stage_tile(E, &lds[0][0], t0 * RB, w, lane);
    asm volatile("s_waitcnt vmcnt(0)" ::: "memory");
    __syncthreads();

    // Anchor B-fragments: def/use point after the drain keeps the loads
    // hoisted and the values resident in VGPRs across the tile loop.
    #pragma unroll
    for (int kk = 0; kk < 4; ++kk)
        #pragma unroll
        for (int cfl = 0; cfl < 2; ++cfl)
            asm volatile("" : "+v"(bh[kk][cfl]), "+v"(bl[kk][cfl]));

    int cur = 0;
    for (int t = t0; t < NTILES; t += GRID_E) {
        const int tn = t + GRID_E;
        // Phase 1: issue next tile's stage (latency hides under compute).
        if (tn < NTILES) stage_tile(E, &lds[cur ^ 1][0], tn * RB, w, lane);

        // Phase 2: compute current tile from lds[cur].
        const float* L = &lds[cur][0];
        f32x4 acc[4][2];
        #pragma unroll
        for (int rf = 0; rf < 4; ++rf)
            #pragma unroll
            for (int cfl = 0; cfl < 2; ++cfl)
                acc[rf][cfl] = (f32x4){0.f, 0.f, 0.f, 0.f};

        #pragma unroll
        for (int kk = 0; kk < 4; ++kk) {
            // A-frag: row r = rf*16+lrow, 16B slot = (kk*8+lk*2+{0,1}) ^ (r&15)
            F16x8U a16[4];
            #pragma unroll
            for (int rf = 0; rf < 4; ++rf) {
                const int r  = rf * 16 + lrow;
                const int q0 = kk * 8 + lk * 2;
                F32x4U x, y;
                x.v = *(const f32x4*)&L[(r * 32 + ((q0    ) ^ (r & 15))) * 4];
                y.v = *(const f32x4*)&L[(r * 32 + ((q0 + 1) ^ (r & 15))) * 4];
                #pragma unroll
                for (int j = 0; j < 4; ++j) {
                    a16[rf].h[j]     = (_Float16)x.f[j];
                    a16[rf].h[j + 4] = (_Float16)y.f[j];
                }
            }
            #pragma unroll
            for (int rf = 0; rf < 4; ++rf)
                #pragma unroll
                for (int cfl = 0; cfl < 2; ++cfl) {
                    acc[rf][cfl] = __builtin_amdgcn_mfma_f32_16x16x32_f16(
                        a16[rf].v, bh[kk][cfl], acc[rf][cfl], 0, 0, 0);
                    acc[rf][cfl] = __builtin_amdgcn_mfma_f32_16x16x32_f16(
                        a16[rf].v, bl[kk][cfl], acc[rf][cfl], 0, 0, 0);
                }
        }

        // Phase 3: drain next-tile stage + barrier (loads were issued one
        // full compute phase ago -> near-zero exposed wait). All waves'
        // ds_reads are already consumed into VGPRs (MFMA deps force lgkm),
        // so re-staging lds[cur] next iteration is race-free.
        if (tn < NTILES) {
            asm volatile("s_waitcnt vmcnt(0)" ::: "memory");
            __syncthreads();
        }

        // Phase 4: store tile t (pure global stores from regs; overlaps the
        // next iteration's compute window).
        const int rb = t * RB;
        #pragma unroll
        for (int rf = 0; rf < 4; ++rf)
            #pragma unroll
            for (int i = 0; i < 4; ++i) {
                const int row = rb + rf * 16 + lk * 4 + i;
                if (row < NROWS) {
                    f16x2 o;
                    o[0] = (_Float16)acc[rf][0][i];
                    o[1] = (_Float16)acc[rf][1][i];
                    *(f16x2*)(Ep + (size_t)row * D + lrow * 8 + w * 2) = o;
                }
            }

        cur ^= 1;
    }
}

// ---------------------------------------------------------------------------
// Kernel 2: out[b] = sigmoid(2 * dot(Ep16[xs[b]], N[ys[b]]) - 1).
// Ep fp16 in pi order: lane l's f16x8 slot j holds col c = l + 16j, pairing
// with N[y][l + 16j] (fp32, exact; 64B-coalesced per 16-lane group).
// ---------------------------------------------------------------------------
__global__ __launch_bounds__(256) void gather_dotN(
    const int* __restrict__ xs, const int* __restrict__ ys,
    const _Float16* __restrict__ Ep, const float* __restrict__ N,
    float* __restrict__ out)
{
    const int tid = threadIdx.x;
    const int o0  = blockIdx.x * 32 + (tid >> 4) * 2;
    const int l   = tid & 15;

    const int x0 = xs[o0], x1 = xs[o0 + 1];
    const int y0 = ys[o0], y1 = ys[o0 + 1];

    const f16x8 a0 = *(const f16x8*)(Ep + (size_t)x0 * D + l * 8);
    const f16x8 a1 = *(const f16x8*)(Ep + (size_t)x1 * D + l * 8);
    const float* n0 = N + (size_t)y0 * D + l;
    const float* n1 = N + (size_t)y1 * D + l;

    float r0 = 0.f, r1 = 0.f;
    #pragma unroll
    for (int j = 0; j < 8; ++j) {
        r0 += (float)a0[j] * n0[16 * j];
        r1 += (float)a1[j] * n1[16 * j];
    }

    r0 += __shfl_xor(r0, 1); r1 += __shfl_xor(r1, 1);
    r0 += __shfl_xor(r0, 2); r1 += __shfl_xor(r1, 2);
    r0 += __shfl_xor(r0, 4); r1 += __shfl_xor(r1, 4);
    r0 += __shfl_xor(r0, 8); r1 += __shfl_xor(r1, 8);

    if (l == 0) {
        float2 v;
        v.x = 1.0f / (1.0f + __expf(1.0f - 2.0f * r0));
        v.y = 1.0f / (1.0f + __expf(1.0f - 2.0f * r1));
        *(float2*)(out + o0) = v;
    }
}

extern "C" void kernel_launch(void* const* d_in, const int* in_sizes, int n_in,
                              void* d_out, int out_size, void* d_ws, size_t ws_size,
                              hipStream_t stream) {
    const int*   xs     = (const int*)d_in[0];
    const int*   ys     = (const int*)d_in[1];
    const float* metric = (const float*)d_in[2];
    const float* EMBEDM = (const float*)d_in[3];
    const float* NEGEM  = (const float*)d_in[4];
    float*       out    = (float*)d_out;

    const int B = in_sizes[0];  // 262144

    // d_ws layout: Ep16 25.6MB @0, M-frag fp16 hi/lo @64MB.
    char* ws = (char*)d_ws;
    _Float16* Ep = (_Float16*)ws;
    _Float16* mh = (_Float16*)(ws + (64u << 20));
    _Float16* ml = (_Float16*)(ws + (64u << 20) + (64u << 10));

    convert_M16<<<8, 256, 0, stream>>>(metric, mh, ml);

    gemm_E<<<GRID_E, 256, 0, stream>>>(EMBEDM, mh, ml, Ep);

    gather_dotN<<<B / 32, 256, 0, stream>>>(xs, ys, Ep, NEGEM, out);
}